// Round 1
// baseline (322.699 us; speedup 1.0000x reference)
//
#include <hip/hip_runtime.h>

// YOLO loss, MI355X. pred [256, 2704, 9, 5] fp32 (124.6 MB) -> scalar.
// Memory-bound: floor = 124.6MB / ~6.9TB/s ~= 18us for the big pass.
//
// This revision vs previous (187us):
//  - fast sigmoid via v_rcp_f32 (kills 3 IEEE div sequences/element, ~21 VALU
//    ops/elem): big pass returns to memory-bound.
//  - no LDS staging: each thread owns 4 consecutive elements = 20 floats =
//    exactly 5 float4 loads; stride-5 redistribution becomes free register
//    indexing (static unroll). No barriers in the hot loop.
//  - 2 launches instead of 4 enqueued ops: obj kernel also zero-inits the
//    accumulator region (stream order makes it visible), noobj kernel does
//    the final combine in the last-finished block (counter + threadfence;
//    bucket read-back via atomicAdd(p, 0.0f) for cross-XCD coherence).
//
// ws layout (floats):
//  [0] coor_sq_obj  [1] conf_sq_obj  [2] coor_obj(label)  [3] conf_obj(iou)
//  [4 .. 4+256)        coor buckets (atomic)
//  [4+256 .. 4+512)    conf buckets (atomic)
//  [516]               completion counter (as int)

#define GHW     52
#define GCELLS  2704          // 52*52
#define NA      9
#define BATCH   256
#define NBLK    (GCELLS * NA) // 24336; NBLK*BATCH == 6,230,016 elements exactly
#define INV52   (1.0f / 52.0f)
#define NBUCKET 256
#define NB2     3042          // noobj grid: 3042 blk * 256 thr * 8 elem = 6,230,016
#define CNT_IDX (4 + 2 * NBUCKET)

__device__ __forceinline__ float sigmoid_exact(float x) {
    return 1.0f / (1.0f + __expf(-x));      // IEEE div; only used in tiny obj kernel
}

__device__ __forceinline__ float sigmoid_fast(float x) {
    return __builtin_amdgcn_rcpf(1.0f + __expf(-x));  // v_rcp_f32, ~1 ulp
}

__device__ __forceinline__ float waveReduceSum(float v) {
#pragma unroll
    for (int o = 32; o > 0; o >>= 1) v += __shfl_down(v, o, 64);
    return v;
}

// ---------------- Kernel A: per-sample responsible box, IoU, obj sums -------
// Also zero-inits buckets + counter (replaces the hipMemsetAsync launch).
__global__ __launch_bounds__(256) void yolo_obj_kernel(
        const float* __restrict__ pred,
        const float* __restrict__ label,
        const float* __restrict__ anchors,
        float* __restrict__ ws) {
    __shared__ float anch[18];
    __shared__ float red[4][4];
    int b = threadIdx.x;

    // zero accumulator region for the noobj kernel (runs after us on the stream)
    ws[4 + b] = 0.0f;
    ws[4 + NBUCKET + b] = 0.0f;
    if (b == 0) ((int*)ws)[CNT_IDX] = 0;

    if (b < 18) anch[b] = anchors[b];
    __syncthreads();

    float4 lab = ((const float4*)label)[b];
    float lx = lab.x, ly = lab.y, lw = lab.z, lh = lab.w;

    int ix = (int)floorf(lx * 52.0f);
    int iy = (int)floorf(ly * 52.0f);
    int idx = ix * GHW + iy;

    // argmax over anchors of squared distance (first-max, strict >)
    int am = 0; float best = -1.0f;
#pragma unroll
    for (int a = 0; a < NA; ++a) {
        float dw = lw - anch[2 * a];
        float dh = lh - anch[2 * a + 1];
        float d = dw * dw + dh * dh;
        if (d > best) { best = d; am = a; }
    }

    const float* p = pred + (((size_t)b * GCELLS + idx) * NA + am) * 5;
    float v0 = p[0], v1 = p[1], v2 = p[2], v3 = p[3], v4 = p[4];

    float aw = anch[2 * am], ah = anch[2 * am + 1];
    float px = (sigmoid_exact(v0) + (float)ix) * INV52;
    float py = (sigmoid_exact(v1) + (float)iy) * INV52;
    float pw = aw * __expf(v2);
    float ph = ah * __expf(v3);
    float pc = sigmoid_exact(v4);

    float agx = ((float)ix + 0.5f) * INV52;
    float agy = ((float)iy + 0.5f) * INV52;

    float d0 = px - agx, d1 = py - agy, d2 = pw - aw, d3 = ph - ah;
    float coor_sq_obj = d0 * d0 + d1 * d1 + d2 * d2 + d3 * d3;
    float conf_sq_obj = pc * pc;

    float e0 = px - lx, e1 = py - ly, e2 = pw - lw, e3 = ph - lh;
    float coor_obj = e0 * e0 + e1 * e1 + e2 * e2 + e3 * e3;

    // IoU (faithful: areas = x2*y2, not (x2-x1)*(y2-y1))
    float lx1 = fmaxf(lx - lw * 0.5f, 0.0f), ly1 = fmaxf(ly - lh * 0.5f, 0.0f);
    float lx2 = fminf(lx + lw * 0.5f, 1.0f), ly2 = fminf(ly + lh * 0.5f, 1.0f);
    float qx1 = fmaxf(px - pw * 0.5f, 0.0f), qy1 = fmaxf(py - ph * 0.5f, 0.0f);
    float qx2 = fminf(px + pw * 0.5f, 1.0f), qy2 = fminf(py + ph * 0.5f, 1.0f);
    float ix1 = fmaxf(lx1, qx1), iy1 = fmaxf(ly1, qy1);
    float ix2 = fminf(lx2, qx2), iy2 = fminf(ly2, qy2);
    float la = lx2 * ly2, pa = qx2 * qy2;
    float inter = fmaxf(ix2 - ix1, 0.0f) * fmaxf(iy2 - iy1, 0.0f);
    float iou = inter / (la + pa - inter);
    float dcf = pc - iou;
    float conf_obj = dcf * dcf;

    float r0 = waveReduceSum(coor_sq_obj);
    float r1 = waveReduceSum(conf_sq_obj);
    float r2 = waveReduceSum(coor_obj);
    float r3 = waveReduceSum(conf_obj);
    int lane = threadIdx.x & 63, wid = threadIdx.x >> 6;
    if (lane == 0) {
        red[0][wid] = r0; red[1][wid] = r1; red[2][wid] = r2; red[3][wid] = r3;
    }
    __syncthreads();
    if (threadIdx.x < 4) {
        ws[threadIdx.x] = red[threadIdx.x][0] + red[threadIdx.x][1]
                        + red[threadIdx.x][2] + red[threadIdx.x][3];
    }
}

// ---------------- Kernel B: noobj reduction (124.6 MB pass) + final combine -
// Each thread: 2 tasks x 4 consecutive elements = 40 floats = 10 float4 loads.
// No LDS staging, no barriers in the hot path.
__global__ __launch_bounds__(256) void yolo_noobj_kernel(
        const float* __restrict__ pred,
        const float* __restrict__ anchors,
        float* __restrict__ ws,
        float* __restrict__ out) {
    __shared__ float anch[18];
    __shared__ float red[2][4];
    __shared__ int isLast;
    int t = threadIdx.x;
    if (t < 18) anch[t] = anchors[t];
    __syncthreads();

    const float4* __restrict__ g4 = (const float4*)pred;
    float coorAcc = 0.0f, confAcc = 0.0f;

#pragma unroll
    for (int it = 0; it < 2; ++it) {
        int task = blockIdx.x * 512 + it * 256 + t;   // < 1,557,504
        size_t fb = (size_t)task * 5;
        float4 q0 = g4[fb + 0];
        float4 q1 = g4[fb + 1];
        float4 q2 = g4[fb + 2];
        float4 q3 = g4[fb + 3];
        float4 q4 = g4[fb + 4];
        float v[20] = {q0.x, q0.y, q0.z, q0.w,
                       q1.x, q1.y, q1.z, q1.w,
                       q2.x, q2.y, q2.z, q2.w,
                       q3.x, q3.y, q3.z, q3.w,
                       q4.x, q4.y, q4.z, q4.w};
        int a = (task * 4) % NA;
#pragma unroll
        for (int j = 0; j < 4; ++j) {                 // static indices -> registers
            float aw = anch[2 * a], ah = anch[2 * a + 1];
            float s0 = sigmoid_fast(v[5 * j + 0]);
            float s1 = sigmoid_fast(v[5 * j + 1]);
            float s4 = sigmoid_fast(v[5 * j + 4]);
            float t0 = (s0 - 0.5f) * INV52;           // == pred_x - anchors_grid_x
            float t1 = (s1 - 0.5f) * INV52;
            float t2 = aw * (__expf(v[5 * j + 2]) - 1.0f);  // == pred_w - anchor_w
            float t3 = ah * (__expf(v[5 * j + 3]) - 1.0f);
            coorAcc += t0 * t0 + t1 * t1 + t2 * t2 + t3 * t3;
            confAcc += s4 * s4;
            a = (a == NA - 1) ? 0 : a + 1;
        }
    }

    float rc = waveReduceSum(coorAcc);
    float rf = waveReduceSum(confAcc);
    int lane = t & 63, wid = t >> 6;
    if (lane == 0) { red[0][wid] = rc; red[1][wid] = rf; }
    __syncthreads();
    if (t == 0) {
        float cs = red[0][0] + red[0][1] + red[0][2] + red[0][3];
        float fs = red[1][0] + red[1][1] + red[1][2] + red[1][3];
        int bk = blockIdx.x & (NBUCKET - 1);          // ~12 blocks/bucket
        atomicAdd(&ws[4 + bk], cs);
        atomicAdd(&ws[4 + NBUCKET + bk], fs);
        __threadfence();                               // buckets visible before counter
        int old = atomicAdd((int*)ws + CNT_IDX, 1);
        isLast = (old == NB2 - 1);
    }
    __syncthreads();

    if (isLast) {
        // all buckets complete; read via device-scope atomics (cross-XCD safe)
        float c = atomicAdd(&ws[4 + t], 0.0f);
        float f = atomicAdd(&ws[4 + NBUCKET + t], 0.0f);
        float rc2 = waveReduceSum(c);
        float rf2 = waveReduceSum(f);
        if (lane == 0) { red[0][wid] = rc2; red[1][wid] = rf2; }
        __syncthreads();
        if (t == 0) {
            float coor_all = red[0][0] + red[0][1] + red[0][2] + red[0][3];
            float conf_all = red[1][0] + red[1][1] + red[1][2] + red[1][3];
            // ws[0..3] written by yolo_obj_kernel (prior dispatch, coherent)
            float coor_l_noobj = (coor_all - ws[0]) / (float)(BATCH * (NBLK - 1) * 4);
            float conf_l_noobj = (conf_all - ws[1]) / (float)(BATCH * (NBLK - 1));
            float coor_l_obj = ws[2] / (float)(BATCH * 4);
            float conf_l_obj = ws[3] / (float)BATCH;
            out[0] = coor_l_obj + coor_l_noobj + conf_l_obj + conf_l_noobj;
        }
    }
}

extern "C" void kernel_launch(void* const* d_in, const int* in_sizes, int n_in,
                              void* d_out, int out_size, void* d_ws, size_t ws_size,
                              hipStream_t stream) {
    const float* pred    = (const float*)d_in[0];
    const float* label   = (const float*)d_in[1];
    const float* anchors = (const float*)d_in[2];
    float* out = (float*)d_out;
    float* ws  = (float*)d_ws;

    yolo_obj_kernel<<<1, 256, 0, stream>>>(pred, label, anchors, ws);
    yolo_noobj_kernel<<<NB2, 256, 0, stream>>>(pred, anchors, ws, out);
}

// Round 2
// 251.452 us; speedup vs baseline: 1.2833x; 1.2833x over previous
//
#include <hip/hip_runtime.h>

// YOLO loss, MI355X. pred [256, 2704, 9, 5] fp32 (124.6 MB) -> scalar.
// Memory-bound: floor = 124.6MB / ~6.3TB/s ~= 20us for the big pass (less if
// pred is L3-resident, which round-1 FETCH_SIZE=61MB suggests it partly is).
//
// Round-1 lesson: thread-owns-5-consecutive-float4s gave 80B lane stride ->
// uncoalesced (64 transactions/instr), 325 GB/s, 192us. This revision:
//  - COALESCED float4 loads: lane i reads float4 q0+i; grid-stride slabs.
//  - per-FLOAT branchless compute (c = F%5 selects channel math; a=(F/5)%9
//    selects anchor). One exp + one rcp per float: u=exp(+-x) serves both
//    sigmoid (c in {0,1,4}) and exp (c in {2,3}) paths.
//  - anchors in 18-float LDS table: addrs 0..17 = distinct banks, conflict-free.
//  - 2 launches total; last-finished block of the big kernel does the final
//    combine (counter + threadfence, atomic read-back for cross-XCD coherence).
//
// ws layout (floats):
//  [0] coor_sq_obj  [1] conf_sq_obj  [2] coor_obj(label)  [3] conf_obj(iou)
//  [4 .. 4+256)        coor buckets (atomic)
//  [4+256 .. 4+512)    conf buckets (atomic)
//  [516]               completion counter (as int)

#define GHW     52
#define GCELLS  2704          // 52*52
#define NA      9
#define BATCH   256
#define NBLK    (GCELLS * NA) // 24336 elements/sample; NBLK*BATCH = 6,230,016
#define INV52   (1.0f / 52.0f)
#define NBUCKET 256
#define CNT_IDX (4 + 2 * NBUCKET)

#define NQ4     7787520u      // total float4s = 6,230,016 * 5 / 4 (exact)
#define NB2     2028          // grid; 2028*256*15 == 7,787,520 exactly
#define ITERQ   15
#define STRIDEQ (NB2 * 256u)  // 519,168 float4s = 8.3MB slab per iteration

__device__ __forceinline__ float sigmoid_exact(float x) {
    return 1.0f / (1.0f + __expf(-x));      // IEEE div; only in tiny obj kernel
}

__device__ __forceinline__ float waveReduceSum(float v) {
#pragma unroll
    for (int o = 32; o > 0; o >>= 1) v += __shfl_down(v, o, 64);
    return v;
}

// ---------------- Kernel A: per-sample responsible box, IoU, obj sums -------
// Also zero-inits buckets + counter (replaces a hipMemsetAsync launch).
__global__ __launch_bounds__(256) void yolo_obj_kernel(
        const float* __restrict__ pred,
        const float* __restrict__ label,
        const float* __restrict__ anchors,
        float* __restrict__ ws) {
    __shared__ float anch[18];
    __shared__ float red[4][4];
    int b = threadIdx.x;

    // zero accumulator region for the noobj kernel (stream order => visible)
    ws[4 + b] = 0.0f;
    ws[4 + NBUCKET + b] = 0.0f;
    if (b == 0) ((int*)ws)[CNT_IDX] = 0;

    if (b < 18) anch[b] = anchors[b];
    __syncthreads();

    float4 lab = ((const float4*)label)[b];
    float lx = lab.x, ly = lab.y, lw = lab.z, lh = lab.w;

    int ix = (int)floorf(lx * 52.0f);
    int iy = (int)floorf(ly * 52.0f);
    int idx = ix * GHW + iy;

    // argmax over anchors of squared distance (first-max, strict >)
    int am = 0; float best = -1.0f;
#pragma unroll
    for (int a = 0; a < NA; ++a) {
        float dw = lw - anch[2 * a];
        float dh = lh - anch[2 * a + 1];
        float d = dw * dw + dh * dh;
        if (d > best) { best = d; am = a; }
    }

    const float* p = pred + (((size_t)b * GCELLS + idx) * NA + am) * 5;
    float v0 = p[0], v1 = p[1], v2 = p[2], v3 = p[3], v4 = p[4];

    float aw = anch[2 * am], ah = anch[2 * am + 1];
    float px = (sigmoid_exact(v0) + (float)ix) * INV52;
    float py = (sigmoid_exact(v1) + (float)iy) * INV52;
    float pw = aw * __expf(v2);
    float ph = ah * __expf(v3);
    float pc = sigmoid_exact(v4);

    float agx = ((float)ix + 0.5f) * INV52;
    float agy = ((float)iy + 0.5f) * INV52;

    float d0 = px - agx, d1 = py - agy, d2 = pw - aw, d3 = ph - ah;
    float coor_sq_obj = d0 * d0 + d1 * d1 + d2 * d2 + d3 * d3;
    float conf_sq_obj = pc * pc;

    float e0 = px - lx, e1 = py - ly, e2 = pw - lw, e3 = ph - lh;
    float coor_obj = e0 * e0 + e1 * e1 + e2 * e2 + e3 * e3;

    // IoU (faithful: areas = x2*y2, not (x2-x1)*(y2-y1))
    float lx1 = fmaxf(lx - lw * 0.5f, 0.0f), ly1 = fmaxf(ly - lh * 0.5f, 0.0f);
    float lx2 = fminf(lx + lw * 0.5f, 1.0f), ly2 = fminf(ly + lh * 0.5f, 1.0f);
    float qx1 = fmaxf(px - pw * 0.5f, 0.0f), qy1 = fmaxf(py - ph * 0.5f, 0.0f);
    float qx2 = fminf(px + pw * 0.5f, 1.0f), qy2 = fminf(py + ph * 0.5f, 1.0f);
    float ix1 = fmaxf(lx1, qx1), iy1 = fmaxf(ly1, qy1);
    float ix2 = fminf(lx2, qx2), iy2 = fminf(ly2, qy2);
    float la = lx2 * ly2, pa = qx2 * qy2;
    float inter = fmaxf(ix2 - ix1, 0.0f) * fmaxf(iy2 - iy1, 0.0f);
    float iou = inter / (la + pa - inter);
    float dcf = pc - iou;
    float conf_obj = dcf * dcf;

    float r0 = waveReduceSum(coor_sq_obj);
    float r1 = waveReduceSum(conf_sq_obj);
    float r2 = waveReduceSum(coor_obj);
    float r3 = waveReduceSum(conf_obj);
    int lane = threadIdx.x & 63, wid = threadIdx.x >> 6;
    if (lane == 0) {
        red[0][wid] = r0; red[1][wid] = r1; red[2][wid] = r2; red[3][wid] = r3;
    }
    __syncthreads();
    if (threadIdx.x < 4) {
        ws[threadIdx.x] = red[threadIdx.x][0] + red[threadIdx.x][1]
                        + red[threadIdx.x][2] + red[threadIdx.x][3];
    }
}

// ---------------- Kernel B: noobj reduction (124.6 MB pass) + final combine -
// Coalesced: lane i loads float4 (base + i). Per-float branchless channel math.
__global__ __launch_bounds__(256) void yolo_noobj_kernel(
        const float* __restrict__ pred,
        const float* __restrict__ anchors,
        float* __restrict__ ws,
        float* __restrict__ out) {
    __shared__ float anch[18];
    __shared__ float red[2][4];
    __shared__ int isLast;
    int t = threadIdx.x;
    if (t < 18) anch[t] = anchors[t];
    __syncthreads();

    const float4* __restrict__ g4 = (const float4*)pred;
    float coorAcc = 0.0f, confAcc = 0.0f;
    unsigned q0 = (unsigned)blockIdx.x * 256u + (unsigned)t;

#pragma unroll
    for (int i = 0; i < ITERQ; ++i) {
        unsigned q = q0 + (unsigned)i * STRIDEQ;   // < 7,787,520
        float4 x4 = g4[q];
        float xs[4] = {x4.x, x4.y, x4.z, x4.w};

        unsigned F0 = q * 4u;                      // flat float index, < 2^25
        unsigned e  = F0 / 5u;                     // const-div -> magic mul
        unsigned c  = F0 - 5u * e;                 // channel 0..4
        unsigned a  = e % 9u;                      // anchor 0..8

#pragma unroll
        for (int k = 0; k < 4; ++k) {
            float x = xs[k];
            bool isWH = (c == 2u) | (c == 3u);
            float u = __expf(isWH ? x : -x);               // one transcendental
            float s = __builtin_amdgcn_rcpf(1.0f + u);     // sigmoid (~1 ulp)
            float aval = anch[2u * a + (c & 1u)];          // in [0,17] for all c
            float d = isWH ? (aval * (u - 1.0f))           // pred_wh - anchor_wh
                           : ((s - 0.5f) * INV52);         // pred_xy - grid_xy
            bool isConf = (c == 4u);
            coorAcc += isConf ? 0.0f : d * d;
            confAcc += isConf ? s * s : 0.0f;
            // advance channel/anchor (predicated, no branch)
            ++c;
            if (c == 5u) { c = 0u; a = (a == 8u) ? 0u : a + 1u; }
        }
    }

    float rc = waveReduceSum(coorAcc);
    float rf = waveReduceSum(confAcc);
    int lane = t & 63, wid = t >> 6;
    if (lane == 0) { red[0][wid] = rc; red[1][wid] = rf; }
    __syncthreads();
    if (t == 0) {
        float cs = red[0][0] + red[0][1] + red[0][2] + red[0][3];
        float fs = red[1][0] + red[1][1] + red[1][2] + red[1][3];
        int bk = blockIdx.x & (NBUCKET - 1);       // ~8 blocks/bucket
        atomicAdd(&ws[4 + bk], cs);
        atomicAdd(&ws[4 + NBUCKET + bk], fs);
        __threadfence();                           // buckets visible before counter
        int old = atomicAdd((int*)ws + CNT_IDX, 1);
        isLast = (old == NB2 - 1);
    }
    __syncthreads();

    if (isLast) {
        // all buckets complete; read via device-scope atomics (cross-XCD safe)
        float c = atomicAdd(&ws[4 + t], 0.0f);
        float f = atomicAdd(&ws[4 + NBUCKET + t], 0.0f);
        float rc2 = waveReduceSum(c);
        float rf2 = waveReduceSum(f);
        if (lane == 0) { red[0][wid] = rc2; red[1][wid] = rf2; }
        __syncthreads();
        if (t == 0) {
            float coor_all = red[0][0] + red[0][1] + red[0][2] + red[0][3];
            float conf_all = red[1][0] + red[1][1] + red[1][2] + red[1][3];
            // ws[0..3] written by yolo_obj_kernel (prior dispatch, coherent)
            float coor_l_noobj = (coor_all - ws[0]) / (float)(BATCH * (NBLK - 1) * 4);
            float conf_l_noobj = (conf_all - ws[1]) / (float)(BATCH * (NBLK - 1));
            float coor_l_obj = ws[2] / (float)(BATCH * 4);
            float conf_l_obj = ws[3] / (float)BATCH;
            out[0] = coor_l_obj + coor_l_noobj + conf_l_obj + conf_l_noobj;
        }
    }
}

extern "C" void kernel_launch(void* const* d_in, const int* in_sizes, int n_in,
                              void* d_out, int out_size, void* d_ws, size_t ws_size,
                              hipStream_t stream) {
    const float* pred    = (const float*)d_in[0];
    const float* label   = (const float*)d_in[1];
    const float* anchors = (const float*)d_in[2];
    float* out = (float*)d_out;
    float* ws  = (float*)d_ws;

    yolo_obj_kernel<<<1, 256, 0, stream>>>(pred, label, anchors, ws);
    yolo_noobj_kernel<<<NB2, 256, 0, stream>>>(pred, anchors, ws, out);
}